// Round 12
// baseline (146.919 us; speedup 1.0000x reference)
//
#include <hip/hip_runtime.h>
#include <stdint.h>

#define EPSF 1e-8f

using i32x4 = __attribute__((ext_vector_type(4))) int;

__device__ __forceinline__ float wave_sum(float v) {
#pragma unroll
  for (int off = 32; off > 0; off >>= 1) v += __shfl_down(v, off, 64);
  return v;
}
__device__ __forceinline__ float wave_max(float v) {
#pragma unroll
  for (int off = 32; off > 0; off >>= 1) v = fmaxf(v, __shfl_down(v, off, 64));
  return v;
}

// ---------------- fused prep: wquant (blocks 0..Dout-1) + xnorm (rest) ----
__global__ __launch_bounds__(256) void prep_kernel(
    const float* __restrict__ x, const float* __restrict__ g,
    const float* __restrict__ w, const float* __restrict__ row_scale,
    signed char* __restrict__ xq, float* __restrict__ sx,
    signed char* __restrict__ wq, float* __restrict__ scale,
    int K, int Dout) {
  __shared__ float smA[4], smQ[4], smM[4];
  const int t = threadIdx.x;
  const int wid = t >> 6;
  if ((int)blockIdx.x < Dout) {
    const int row = blockIdx.x;
    const float* wr = w + (size_t)row * K;
    float4 v0 = reinterpret_cast<const float4*>(wr)[2 * t];
    float4 v1 = reinterpret_cast<const float4*>(wr)[2 * t + 1];
    float f[8] = {v0.x, v0.y, v0.z, v0.w, v1.x, v1.y, v1.z, v1.w};
    float sa = 0.f, sq = 0.f;
#pragma unroll
    for (int i = 0; i < 8; ++i) { sa += fabsf(f[i]); sq += f[i] * f[i]; }
    sa = wave_sum(sa);
    sq = wave_sum(sq);
    if ((t & 63) == 0) { smA[wid] = sa; smQ[wid] = sq; }
    __syncthreads();
    const float sumabs = smA[0] + smA[1] + smA[2] + smA[3];
    const float sumsq  = smQ[0] + smQ[1] + smQ[2] + smQ[3];
    const float absmean = sumabs / (float)K;
    const float thr = 0.5f * absmean;
    union { signed char c[8]; uint2 u; } pk;
#pragma unroll
    for (int i = 0; i < 8; ++i)
      pk.c[i] = (fabsf(f[i]) > thr)
                    ? (f[i] > 0.f ? (signed char)1 : (signed char)-1)
                    : (signed char)0;
    reinterpret_cast<uint2*>(wq + (size_t)row * K)[t] = pk.u;
    if (t == 0)
      scale[row] = absmean * rsqrtf(sumsq / (float)K + EPSF) * row_scale[row];
  } else {
    const int row = blockIdx.x - Dout;
    const float* xr = x + (size_t)row * K;
    float4 v0 = reinterpret_cast<const float4*>(xr)[2 * t];
    float4 v1 = reinterpret_cast<const float4*>(xr)[2 * t + 1];
    float f[8] = {v0.x, v0.y, v0.z, v0.w, v1.x, v1.y, v1.z, v1.w};
    float sq = 0.f;
#pragma unroll
    for (int i = 0; i < 8; ++i) sq += f[i] * f[i];
    sq = wave_sum(sq);
    if ((t & 63) == 0) smQ[wid] = sq;
    __syncthreads();
    const float sumsq = smQ[0] + smQ[1] + smQ[2] + smQ[3];
    const float rs = rsqrtf(sumsq / (float)K + EPSF);
    float4 g0 = reinterpret_cast<const float4*>(g)[2 * t];
    float4 g1 = reinterpret_cast<const float4*>(g)[2 * t + 1];
    float gg[8] = {g0.x, g0.y, g0.z, g0.w, g1.x, g1.y, g1.z, g1.w};
    float vv[8]; float am = 0.f;
#pragma unroll
    for (int i = 0; i < 8; ++i) {
      vv[i] = f[i] * rs * gg[i];
      am = fmaxf(am, fabsf(vv[i]));
    }
    am = wave_max(am);
    if ((t & 63) == 0) smM[wid] = am;
    __syncthreads();
    const float amax = fmaxf(fmaxf(smM[0], smM[1]), fmaxf(smM[2], smM[3]));
    const float inv = amax > 0.f ? 127.f / amax : 0.f;
    union { signed char c[8]; uint2 u; } pk;
#pragma unroll
    for (int i = 0; i < 8; ++i)
      pk.c[i] = (signed char)__float2int_rn(vv[i] * inv);
    reinterpret_cast<uint2*>(xq + (size_t)row * K)[t] = pk.u;
    if (t == 0) sx[row] = amax > 0.f ? amax / 127.f : 0.f;
  }
}

// ---------------- i8 NT GEMM, 256x256, A-in-LDS + B-direct-to-VGPR ----------
// ROUND-12: B bypasses LDS entirely. Invariant found R6-R11: time ~= LDS
// cycles + MFMA cycles SUMMED; only reducing LDS traffic helps. B panel is
// 4 MB (L2-resident per XCD under chunked swizzle); B fragments load
// global->VGPR with compiler-inserted counted vmcnt (no barrier coupling),
// one phase ahead of use. LDS/tile: 256 KB -> 160 KB (-37%); stage loads
// per iter 16 -> 8. A path (stage/swizzle/ds_read/phases) = R6 verbatim.
// B banks (32 VGPR): bN0 = np0 frags, loaded P8(prev)/P4, used P1,P3/P5,P7;
// bN1 = np1, loaded P1/P5, used P2,P4/P6,P8. Reload-after-last-use (WAR in
// program order). No B swizzle needed (A's store+read swizzle cancels; both
// operands see the same linear k -> any frag k-permutation cancels in dot).
// vmcnt ledger (per-thread loads: P1 SA2+LB4, P3 SA2, P4 LB4, P5 SA2+LB4,
// P7 SA2, P8 LB4; worst-case intra-phase order assumed):
//  VM@P1 needs SA(prev P3): after = 4+6+2+4 = 16        -> VM(16)
//  VM@P3 needs SA(prev P5): worst after = 4+2+4+6 = 16? LB@P5 may precede
//    SA -> after = 2+4+6 = 12                            -> VM(12)
//  VM@P5 needs SA(prev P7): after = 4+6+2+4 = 16        -> VM(16)
//  VM@P7 needs SA(this P1): worst after = 2+4+6 = 12    -> VM(12)
// Prologue: [SA x3 (6); sched_barrier; LBN0(t0) (4); VM(4)] -> drains all SA.
// Peel: P1 VM(16), P3 VM(12), P5 VM(12), P7 VM(8); stores inline P5-P8.

#define BAR() do { __builtin_amdgcn_sched_barrier(0); \
                   asm volatile("" ::: "memory"); \
                   __builtin_amdgcn_s_barrier(); \
                   asm volatile("" ::: "memory"); \
                   __builtin_amdgcn_sched_barrier(0); } while (0)
#define VM(n) asm volatile("s_waitcnt vmcnt(" #n ")" ::: "memory")

__global__ __launch_bounds__(512, 2) void gemm_kernel(
    const signed char* __restrict__ A,   // [M][K] i8 (xq)
    const signed char* __restrict__ B,   // [N][K] i8 ternary (wq)
    const float* __restrict__ scale, const float* __restrict__ bias,
    const float* __restrict__ sx,
    float* __restrict__ C, int M, int N, int K) {
  __shared__ signed char lds[2][2][16384];   // A only: [buf][half][16 KB]

  const int tid  = threadIdx.x;
  const int lane = tid & 63;
  const int wid  = tid >> 6;
  const int wm   = wid >> 2;   // 0..1
  const int wn   = wid & 3;    // 0..3
  const int fr   = lane & 15;
  const int kq   = lane >> 4;

  // chunked XCD swizzle (grid 512 % 8 == 0)
  const int nwg = gridDim.x;
  const int cpx = nwg >> 3;
  const int swz = (blockIdx.x & 7) * cpx + (blockIdx.x >> 3);
  const int NBN = N >> 8;
  const int bn = swz % NBN;
  const int bm = swz / NBN;
  const int mBase = bm * 256, nBase = bn * 256;

  const size_t Kb = (size_t)K;

  // A staging (R6 verbatim): thread t -> lds row sr=t>>3, granule slot t&7;
  // XOR-inverse source granule (valid for +64-row second load: 64&7==0).
  const int sr = tid >> 3;
  const int gsrc = (tid & 7) ^ (sr & 7);
  const char* Abyte = (const char*)A + (size_t)(mBase + sr) * Kb + gsrc * 16;

#define STAGE_A(bufi, h, t) do { \
    __builtin_amdgcn_global_load_lds( \
      (const __attribute__((address_space(1))) void*)(Abyte + (size_t)((h) * 64) * Kb + (size_t)(t) * 128), \
      (__attribute__((address_space(3))) void*)(&lds[bufi][h][tid * 16]), 16, 0, 0); \
    __builtin_amdgcn_global_load_lds( \
      (const __attribute__((address_space(1))) void*)(Abyte + (size_t)(128 + (h) * 64) * Kb + (size_t)(t) * 128), \
      (__attribute__((address_space(3))) void*)(&lds[bufi][h][8192 + tid * 16]), 16, 0, 0); \
  } while (0)

  // A reader constants (R6 verbatim)
  const int slot0 = ((kq ^ (fr & 7)) << 4);
  const int aRowB = (wm * 64 + fr) * 128;

  // B direct-load offsets: col c = nBase + wn*64 + np*32 + nn*16 + fr;
  // byte off = c*K + kq*16 (+ tile*128 + s*64 at load time)
  const uint32_t bo0 = (uint32_t)((nBase + wn * 64 + fr) * K) + kq * 16;
  const uint32_t bo1 = bo0 + (uint32_t)(16 * K);
  const uint32_t bo2 = bo0 + (uint32_t)(32 * K);
  const uint32_t bo3 = bo0 + (uint32_t)(48 * K);

  i32x4 aF[4][2];
  i32x4 bN0[2][2], bN1[2][2];   // [nn][s] for np=0 / np=1
  i32x4 acc[8][4];
#pragma unroll
  for (int m = 0; m < 8; ++m)
#pragma unroll
    for (int n = 0; n < 4; ++n) acc[m][n] = (i32x4){0, 0, 0, 0};

#define LDA(bufi, mg) do { \
    _Pragma("unroll") for (int mm = 0; mm < 4; ++mm) \
    _Pragma("unroll") for (int s = 0; s < 2; ++s) \
      aF[mm][s] = *(const i32x4*)&lds[bufi][mg][ \
          aRowB + mm * 2048 + (slot0 ^ (s << 6))]; \
  } while (0)

#define LBN0(kt) do { \
    const signed char* Bk_ = B + (size_t)(kt) * 128; \
    bN0[0][0] = *(const i32x4*)(Bk_ + bo0); \
    bN0[0][1] = *(const i32x4*)(Bk_ + bo0 + 64); \
    bN0[1][0] = *(const i32x4*)(Bk_ + bo1); \
    bN0[1][1] = *(const i32x4*)(Bk_ + bo1 + 64); \
  } while (0)

#define LBN1(kt) do { \
    const signed char* Bk_ = B + (size_t)(kt) * 128; \
    bN1[0][0] = *(const i32x4*)(Bk_ + bo2); \
    bN1[0][1] = *(const i32x4*)(Bk_ + bo2 + 64); \
    bN1[1][0] = *(const i32x4*)(Bk_ + bo3); \
    bN1[1][1] = *(const i32x4*)(Bk_ + bo3 + 64); \
  } while (0)

#define MFMA_Q(mg, np, bank) do { \
    __builtin_amdgcn_s_setprio(1); \
    _Pragma("unroll") for (int mm = 0; mm < 4; ++mm) \
    _Pragma("unroll") for (int nn = 0; nn < 2; ++nn) { \
      i32x4 c = acc[(mg) * 4 + mm][(np) * 2 + nn]; \
      c = __builtin_amdgcn_mfma_i32_16x16x64_i8(aF[mm][0], bank[nn][0], c, 0, 0, 0); \
      c = __builtin_amdgcn_mfma_i32_16x16x64_i8(aF[mm][1], bank[nn][1], c, 0, 0, 0); \
      acc[(mg) * 4 + mm][(np) * 2 + nn] = c; \
    } \
    __builtin_amdgcn_s_setprio(0); } while (0)

  const int crowBase = mBase + wm * 128 + kq * 4;
  const int ccolBase = nBase + wn * 64 + fr;

#define STORE_Q(mg, np) do { \
    float sxq_[4][4]; \
    _Pragma("unroll") for (int mm = 0; mm < 4; ++mm) \
    _Pragma("unroll") for (int r = 0; r < 4; ++r) \
      sxq_[mm][r] = sx[crowBase + ((mg) * 4 + mm) * 16 + r]; \
    _Pragma("unroll") for (int nn = 0; nn < 2; ++nn) { \
      const int gc = ccolBase + ((np) * 2 + nn) * 16; \
      const float sc = scale[gc]; \
      const float bi = bias[gc]; \
      _Pragma("unroll") for (int mm = 0; mm < 4; ++mm) { \
        const int r0 = crowBase + ((mg) * 4 + mm) * 16; \
        _Pragma("unroll") for (int r = 0; r < 4; ++r) \
          C[(size_t)(r0 + r) * (size_t)N + (size_t)gc] = \
              (float)acc[(mg) * 4 + mm][(np) * 2 + nn][r] * (sxq_[mm][r] * sc) + bi; \
      } } } while (0)

  // ---- prologue: A tiles {buf0 h0,h1; buf1 h0}; B np0(tile0) ----
  STAGE_A(0, 0, 0);
  STAGE_A(0, 1, 0);
  STAGE_A(1, 0, 1);
  __builtin_amdgcn_sched_barrier(0);   // pin SA-before-LB issue order
  LBN0(0);
  VM(4);        // drains all three SA pairs (LBN0's 4 may stay in flight)
  BAR();

  const int NT = K >> 7;  // 2048/128 = 16 K-tiles; 7 iters + peel
  for (int i = 0; i < (NT >> 1) - 1; ++i) {
    const int t0  = 2 * i;
    const int t1  = 2 * i + 1;
    const int tn0 = 2 * i + 2;
    const int tn1 = 2 * i + 3;
    // P1
    VM(16); LDA(0, 0); STAGE_A(1, 1, t1); LBN1(t0);
    BAR(); MFMA_Q(0, 0, bN0);
    // P2
    BAR(); MFMA_Q(0, 1, bN1);
    // P3
    VM(12); LDA(0, 1); STAGE_A(0, 0, tn0);
    BAR(); MFMA_Q(1, 0, bN0);
    // P4
    LBN0(t1);
    BAR(); MFMA_Q(1, 1, bN1);
    // P5
    VM(16); LDA(1, 0); STAGE_A(0, 1, tn0); LBN1(t1);
    BAR(); MFMA_Q(0, 0, bN0);
    // P6
    BAR(); MFMA_Q(0, 1, bN1);
    // P7
    VM(12); LDA(1, 1); STAGE_A(1, 0, tn1);
    BAR(); MFMA_Q(1, 0, bN0);
    // P8
    LBN0(tn0);
    BAR(); MFMA_Q(1, 1, bN1);
  }

  // ---- peeled last pair (tiles NT-2 buf0, NT-1 buf1) ----
  {
    const int tp = NT - 2;
    const int tl = NT - 1;
    // P1
    VM(16); LDA(0, 0); STAGE_A(1, 1, tl); LBN1(tp);
    BAR(); MFMA_Q(0, 0, bN0);
    // P2
    BAR(); MFMA_Q(0, 1, bN1);
    // P3
    VM(12); LDA(0, 1);
    BAR(); MFMA_Q(1, 0, bN0);
    // P4
    LBN0(tl);
    BAR(); MFMA_Q(1, 1, bN1);
    // P5: quadrants final from here -> store inline
    VM(12); LDA(1, 0); LBN1(tl);
    BAR(); MFMA_Q(0, 0, bN0); STORE_Q(0, 0);
    // P6
    BAR(); MFMA_Q(0, 1, bN1); STORE_Q(0, 1);
    // P7
    VM(8); LDA(1, 1);
    BAR(); MFMA_Q(1, 0, bN0); STORE_Q(1, 0);
    // P8
    BAR(); MFMA_Q(1, 1, bN1); STORE_Q(1, 1);
  }
  VM(0);  // safety drain before exit
#undef STAGE_A
#undef LDA
#undef LBN0
#undef LBN1
#undef MFMA_Q
#undef STORE_Q
}

extern "C" void kernel_launch(void* const* d_in, const int* in_sizes, int n_in,
                              void* d_out, int out_size, void* d_ws, size_t ws_size,
                              hipStream_t stream) {
  const float* x         = (const float*)d_in[0];  // [B,S,Din]
  const float* weight    = (const float*)d_in[1];  // [Dout,Din]
  const float* row_scale = (const float*)d_in[2];  // [Dout,1]
  const float* bias      = (const float*)d_in[3];  // [Dout]
  const float* g         = (const float*)d_in[4];  // [Din]
  float* out = (float*)d_out;

  const int Din  = in_sizes[4];         // 2048
  const int Dout = in_sizes[3];         // 2048
  const int Mrows = in_sizes[0] / Din;  // 16384

  // ws: wq i8 [Dout*Din] | xq i8 [M*Din] | scale f32 [Dout] | sx f32 [M]
  char* ws = (char*)d_ws;
  signed char* wq = (signed char*)ws;
  signed char* xq = (signed char*)(ws + (size_t)Dout * Din);
  float* scale = (float*)(ws + (size_t)Dout * Din + (size_t)Mrows * Din);
  float* sx = scale + Dout;

  prep_kernel<<<Dout + Mrows, 256, 0, stream>>>(x, g, weight, row_scale,
                                                xq, sx, wq, scale, Din, Dout);
  const int grid = (Mrows / 256) * (Dout / 256);  // 64 * 8 = 512
  gemm_kernel<<<grid, 512, 0, stream>>>(xq, wq, scale, bias, sx, out,
                                        Mrows, Dout, Din);
}

// Round 13
// 117.169 us; speedup vs baseline: 1.2539x; 1.2539x over previous
//
#include <hip/hip_runtime.h>
#include <stdint.h>

#define EPSF 1e-8f

using i32x4 = __attribute__((ext_vector_type(4))) int;

__device__ __forceinline__ float wave_sum(float v) {
#pragma unroll
  for (int off = 32; off > 0; off >>= 1) v += __shfl_down(v, off, 64);
  return v;
}
__device__ __forceinline__ float wave_max(float v) {
#pragma unroll
  for (int off = 32; off > 0; off >>= 1) v = fmaxf(v, __shfl_down(v, off, 64));
  return v;
}

// ---------------- fused prep: wquant (blocks 0..Dout-1) + xnorm (rest) ----
// wquant writes ternary i8 into MFMA-FRAGMENT layout B2[kt2][ng][lane][16]:
//   kt2 = k/64, ng = col/16, lane = ((k%64)/16)*16 + (col%16)
// so the GEMM's per-wave B-fragment load is one coalesced 1KB dwordx4
// (lane-linear). R12's failure was B loads at stride-K (64 cache lines per
// instr, 4x L2 amplification); this layout makes them 16-line contiguous.
__global__ __launch_bounds__(256) void prep_kernel(
    const float* __restrict__ x, const float* __restrict__ g,
    const float* __restrict__ w, const float* __restrict__ row_scale,
    signed char* __restrict__ xq, float* __restrict__ sx,
    signed char* __restrict__ B2, float* __restrict__ scale,
    int K, int Dout) {
  __shared__ float smA[4], smQ[4], smM[4];
  const int t = threadIdx.x;
  const int wid = t >> 6;
  if ((int)blockIdx.x < Dout) {
    const int o = blockIdx.x;  // weight row = output col
    const float* wr = w + (size_t)o * K;
    float4 v0 = reinterpret_cast<const float4*>(wr)[2 * t];
    float4 v1 = reinterpret_cast<const float4*>(wr)[2 * t + 1];
    float f[8] = {v0.x, v0.y, v0.z, v0.w, v1.x, v1.y, v1.z, v1.w};
    float sa = 0.f, sq = 0.f;
#pragma unroll
    for (int i = 0; i < 8; ++i) { sa += fabsf(f[i]); sq += f[i] * f[i]; }
    sa = wave_sum(sa);
    sq = wave_sum(sq);
    if ((t & 63) == 0) { smA[wid] = sa; smQ[wid] = sq; }
    __syncthreads();
    const float sumabs = smA[0] + smA[1] + smA[2] + smA[3];
    const float sumsq  = smQ[0] + smQ[1] + smQ[2] + smQ[3];
    const float absmean = sumabs / (float)K;
    const float thr = 0.5f * absmean;
    union { signed char c[8]; uint2 u; } pk;
#pragma unroll
    for (int i = 0; i < 8; ++i)
      pk.c[i] = (fabsf(f[i]) > thr)
                    ? (f[i] > 0.f ? (signed char)1 : (signed char)-1)
                    : (signed char)0;
    // fragment-layout address for k = t*8 .. t*8+7 of col o:
    const int kt2 = t >> 3;              // k/64
    const int kq  = (t >> 1) & 3;        // (k%64)/16
    const int half = (t & 1) * 8;        // byte offset within the 16B chunk
    const size_t addr = (size_t)kt2 * ((size_t)(2048 / 16) * 1024)  // K/16? no: N/16 groups
                      ;
    // NOTE: ng stride is (N/16) groups of 1024B per kt2; N == Dout here.
    const size_t a = ((size_t)kt2 * (Dout / 16) + (o >> 4)) * 1024 +
                     (size_t)(kq * 16 + (o & 15)) * 16 + half;
    *reinterpret_cast<uint2*>(B2 + a) = pk.u;
    (void)addr;
    if (t == 0)
      scale[o] = absmean * rsqrtf(sumsq / (float)K + EPSF) * row_scale[o];
  } else {
    const int row = blockIdx.x - Dout;
    const float* xr = x + (size_t)row * K;
    float4 v0 = reinterpret_cast<const float4*>(xr)[2 * t];
    float4 v1 = reinterpret_cast<const float4*>(xr)[2 * t + 1];
    float f[8] = {v0.x, v0.y, v0.z, v0.w, v1.x, v1.y, v1.z, v1.w};
    float sq = 0.f;
#pragma unroll
    for (int i = 0; i < 8; ++i) sq += f[i] * f[i];
    sq = wave_sum(sq);
    if ((t & 63) == 0) smQ[wid] = sq;
    __syncthreads();
    const float sumsq = smQ[0] + smQ[1] + smQ[2] + smQ[3];
    const float rs = rsqrtf(sumsq / (float)K + EPSF);
    float4 g0 = reinterpret_cast<const float4*>(g)[2 * t];
    float4 g1 = reinterpret_cast<const float4*>(g)[2 * t + 1];
    float gg[8] = {g0.x, g0.y, g0.z, g0.w, g1.x, g1.y, g1.z, g1.w};
    float vv[8]; float am = 0.f;
#pragma unroll
    for (int i = 0; i < 8; ++i) {
      vv[i] = f[i] * rs * gg[i];
      am = fmaxf(am, fabsf(vv[i]));
    }
    am = wave_max(am);
    if ((t & 63) == 0) smM[wid] = am;
    __syncthreads();
    const float amax = fmaxf(fmaxf(smM[0], smM[1]), fmaxf(smM[2], smM[3]));
    const float inv = amax > 0.f ? 127.f / amax : 0.f;
    union { signed char c[8]; uint2 u; } pk;
#pragma unroll
    for (int i = 0; i < 8; ++i)
      pk.c[i] = (signed char)__float2int_rn(vv[i] * inv);
    reinterpret_cast<uint2*>(xq + (size_t)row * K)[t] = pk.u;
    if (t == 0) sx[row] = amax > 0.f ? amax / 127.f : 0.f;
  }
}

// ---------------- i8 NT GEMM, 256x256, A-in-LDS + coalesced B-to-VGPR ------
// ROUND-13 = R12 schedule (race-verified) with B loads retargeted at the
// fragment-ordered B2 (lane-linear 1KB per load). LDS holds A only (64 KB,
// double-buffered): per block-K-tile LDS traffic 160 KB vs R6's 256 KB.
// B L2 traffic: 8 KB/wave/K-tile coalesced; B panel 4 MB L2-resident.
// vmcnt ledger identical to R12 (same per-phase load counts:
// P1 SA2+LB4, P3 SA2, P4 LB4, P5 SA2+LB4, P7 SA2, P8 LB4):
//  VM(16)@P1, VM(12)@P3, VM(16)@P5, VM(12)@P7; prologue VM(4);
//  peel VM(16)/VM(12)/VM(12)/VM(8), stores inline P5-P8.

#define BAR() do { __builtin_amdgcn_sched_barrier(0); \
                   asm volatile("" ::: "memory"); \
                   __builtin_amdgcn_s_barrier(); \
                   asm volatile("" ::: "memory"); \
                   __builtin_amdgcn_sched_barrier(0); } while (0)
#define VM(n) asm volatile("s_waitcnt vmcnt(" #n ")" ::: "memory")

__global__ __launch_bounds__(512, 2) void gemm_kernel(
    const signed char* __restrict__ A,    // [M][K] i8 (xq)
    const signed char* __restrict__ B2,   // fragment-ordered ternary weights
    const float* __restrict__ scale, const float* __restrict__ bias,
    const float* __restrict__ sx,
    float* __restrict__ C, int M, int N, int K) {
  __shared__ signed char lds[2][2][16384];   // A only: [buf][half][16 KB]

  const int tid  = threadIdx.x;
  const int lane = tid & 63;
  const int wid  = tid >> 6;
  const int wm   = wid >> 2;   // 0..1
  const int wn   = wid & 3;    // 0..3
  const int fr   = lane & 15;
  const int kq   = lane >> 4;

  // chunked XCD swizzle (grid 512 % 8 == 0)
  const int nwg = gridDim.x;
  const int cpx = nwg >> 3;
  const int swz = (blockIdx.x & 7) * cpx + (blockIdx.x >> 3);
  const int NBN = N >> 8;
  const int bn = swz % NBN;
  const int bm = swz / NBN;
  const int mBase = bm * 256, nBase = bn * 256;

  const size_t Kb = (size_t)K;

  // A staging (R6 verbatim)
  const int sr = tid >> 3;
  const int gsrc = (tid & 7) ^ (sr & 7);
  const char* Abyte = (const char*)A + (size_t)(mBase + sr) * Kb + gsrc * 16;

#define STAGE_A(bufi, h, t) do { \
    __builtin_amdgcn_global_load_lds( \
      (const __attribute__((address_space(1))) void*)(Abyte + (size_t)((h) * 64) * Kb + (size_t)(t) * 128), \
      (__attribute__((address_space(3))) void*)(&lds[bufi][h][tid * 16]), 16, 0, 0); \
    __builtin_amdgcn_global_load_lds( \
      (const __attribute__((address_space(1))) void*)(Abyte + (size_t)(128 + (h) * 64) * Kb + (size_t)(t) * 128), \
      (__attribute__((address_space(3))) void*)(&lds[bufi][h][8192 + tid * 16]), 16, 0, 0); \
  } while (0)

  // A reader constants (R6 verbatim)
  const int slot0 = ((kq ^ (fr & 7)) << 4);
  const int aRowB = (wm * 64 + fr) * 128;

  // B2 fragment addressing: frag(kt2, ng) at ((kt2*(N/16) + ng)*1024);
  // this wave's base ng = nBase/16 + wn*4; np adds 2, nn adds 1.
  const size_t ngStride = 1024;
  const size_t ktStride = (size_t)(N >> 4) * 1024;
  const signed char* B2w = B2 +
      ((size_t)(nBase >> 4) + (size_t)wn * 4) * ngStride + (size_t)lane * 16;

  i32x4 aF[4][2];
  i32x4 bN0[2][2], bN1[2][2];   // [nn][s]
  i32x4 acc[8][4];
#pragma unroll
  for (int m = 0; m < 8; ++m)
#pragma unroll
    for (int n = 0; n < 4; ++n) acc[m][n] = (i32x4){0, 0, 0, 0};

#define LDA(bufi, mg) do { \
    _Pragma("unroll") for (int mm = 0; mm < 4; ++mm) \
    _Pragma("unroll") for (int s = 0; s < 2; ++s) \
      aF[mm][s] = *(const i32x4*)&lds[bufi][mg][ \
          aRowB + mm * 2048 + (slot0 ^ (s << 6))]; \
  } while (0)

  // kt = 128-wide K-tile index; kt2 = 2*kt + s
#define LBN0(kt) do { \
    const signed char* Bk_ = B2w + (size_t)(2 * (kt)) * ktStride; \
    bN0[0][0] = *(const i32x4*)(Bk_); \
    bN0[1][0] = *(const i32x4*)(Bk_ + ngStride); \
    bN0[0][1] = *(const i32x4*)(Bk_ + ktStride); \
    bN0[1][1] = *(const i32x4*)(Bk_ + ktStride + ngStride); \
  } while (0)

#define LBN1(kt) do { \
    const signed char* Bk_ = B2w + (size_t)(2 * (kt)) * ktStride + 2 * ngStride; \
    bN1[0][0] = *(const i32x4*)(Bk_); \
    bN1[1][0] = *(const i32x4*)(Bk_ + ngStride); \
    bN1[0][1] = *(const i32x4*)(Bk_ + ktStride); \
    bN1[1][1] = *(const i32x4*)(Bk_ + ktStride + ngStride); \
  } while (0)

#define MFMA_Q(mg, np, bank) do { \
    __builtin_amdgcn_s_setprio(1); \
    _Pragma("unroll") for (int mm = 0; mm < 4; ++mm) \
    _Pragma("unroll") for (int nn = 0; nn < 2; ++nn) { \
      i32x4 c = acc[(mg) * 4 + mm][(np) * 2 + nn]; \
      c = __builtin_amdgcn_mfma_i32_16x16x64_i8(aF[mm][0], bank[nn][0], c, 0, 0, 0); \
      c = __builtin_amdgcn_mfma_i32_16x16x64_i8(aF[mm][1], bank[nn][1], c, 0, 0, 0); \
      acc[(mg) * 4 + mm][(np) * 2 + nn] = c; \
    } \
    __builtin_amdgcn_s_setprio(0); } while (0)

  const int crowBase = mBase + wm * 128 + kq * 4;
  const int ccolBase = nBase + wn * 64 + fr;

#define STORE_Q(mg, np) do { \
    float sxq_[4][4]; \
    _Pragma("unroll") for (int mm = 0; mm < 4; ++mm) \
    _Pragma("unroll") for (int r = 0; r < 4; ++r) \
      sxq_[mm][r] = sx[crowBase + ((mg) * 4 + mm) * 16 + r]; \
    _Pragma("unroll") for (int nn = 0; nn < 2; ++nn) { \
      const int gc = ccolBase + ((np) * 2 + nn) * 16; \
      const float sc = scale[gc]; \
      const float bi = bias[gc]; \
      _Pragma("unroll") for (int mm = 0; mm < 4; ++mm) { \
        const int r0 = crowBase + ((mg) * 4 + mm) * 16; \
        _Pragma("unroll") for (int r = 0; r < 4; ++r) \
          C[(size_t)(r0 + r) * (size_t)N + (size_t)gc] = \
              (float)acc[(mg) * 4 + mm][(np) * 2 + nn][r] * (sxq_[mm][r] * sc) + bi; \
      } } } while (0)

  // ---- prologue: A tiles {buf0 h0,h1; buf1 h0}; B np0(tile0) ----
  STAGE_A(0, 0, 0);
  STAGE_A(0, 1, 0);
  STAGE_A(1, 0, 1);
  __builtin_amdgcn_sched_barrier(0);   // pin SA-before-LB issue order
  LBN0(0);
  VM(4);        // drains the three SA pairs (LBN0's 4 may stay in flight)
  BAR();

  const int NT = K >> 7;  // 2048/128 = 16 K-tiles; 7 iters + peel
  for (int i = 0; i < (NT >> 1) - 1; ++i) {
    const int t0  = 2 * i;
    const int t1  = 2 * i + 1;
    const int tn0 = 2 * i + 2;
    const int tn1 = 2 * i + 3;
    // P1
    VM(16); LDA(0, 0); STAGE_A(1, 1, t1); LBN1(t0);
    BAR(); MFMA_Q(0, 0, bN0);
    // P2
    BAR(); MFMA_Q(0, 1, bN1);
    // P3
    VM(12); LDA(0, 1); STAGE_A(0, 0, tn0);
    BAR(); MFMA_Q(1, 0, bN0);
    // P4
    LBN0(t1);
    BAR(); MFMA_Q(1, 1, bN1);
    // P5
    VM(16); LDA(1, 0); STAGE_A(0, 1, tn0); LBN1(t1);
    BAR(); MFMA_Q(0, 0, bN0);
    // P6
    BAR(); MFMA_Q(0, 1, bN1);
    // P7
    VM(12); LDA(1, 1); STAGE_A(1, 0, tn1);
    BAR(); MFMA_Q(1, 0, bN0);
    // P8
    LBN0(tn0);
    BAR(); MFMA_Q(1, 1, bN1);
  }

  // ---- peeled last pair (tiles NT-2 buf0, NT-1 buf1) ----
  {
    const int tp = NT - 2;
    const int tl = NT - 1;
    // P1
    VM(16); LDA(0, 0); STAGE_A(1, 1, tl); LBN1(tp);
    BAR(); MFMA_Q(0, 0, bN0);
    // P2
    BAR(); MFMA_Q(0, 1, bN1);
    // P3
    VM(12); LDA(0, 1);
    BAR(); MFMA_Q(1, 0, bN0);
    // P4
    LBN0(tl);
    BAR(); MFMA_Q(1, 1, bN1);
    // P5: quadrants final from here -> store inline
    VM(12); LDA(1, 0); LBN1(tl);
    BAR(); MFMA_Q(0, 0, bN0); STORE_Q(0, 0);
    // P6
    BAR(); MFMA_Q(0, 1, bN1); STORE_Q(0, 1);
    // P7
    VM(8); LDA(1, 1);
    BAR(); MFMA_Q(1, 0, bN0); STORE_Q(1, 0);
    // P8
    BAR(); MFMA_Q(1, 1, bN1); STORE_Q(1, 1);
  }
  VM(0);  // safety drain before exit
#undef STAGE_A
#undef LDA
#undef LBN0
#undef LBN1
#undef MFMA_Q
#undef STORE_Q
}

extern "C" void kernel_launch(void* const* d_in, const int* in_sizes, int n_in,
                              void* d_out, int out_size, void* d_ws, size_t ws_size,
                              hipStream_t stream) {
  const float* x         = (const float*)d_in[0];  // [B,S,Din]
  const float* weight    = (const float*)d_in[1];  // [Dout,Din]
  const float* row_scale = (const float*)d_in[2];  // [Dout,1]
  const float* bias      = (const float*)d_in[3];  // [Dout]
  const float* g         = (const float*)d_in[4];  // [Din]
  float* out = (float*)d_out;

  const int Din  = in_sizes[4];         // 2048
  const int Dout = in_sizes[3];         // 2048
  const int Mrows = in_sizes[0] / Din;  // 16384

  // ws: B2 i8 [Dout*Din] | xq i8 [M*Din] | scale f32 [Dout] | sx f32 [M]
  char* ws = (char*)d_ws;
  signed char* B2 = (signed char*)ws;
  signed char* xq = (signed char*)(ws + (size_t)Dout * Din);
  float* scale = (float*)(ws + (size_t)Dout * Din + (size_t)Mrows * Din);
  float* sx = scale + Dout;

  prep_kernel<<<Dout + Mrows, 256, 0, stream>>>(x, g, weight, row_scale,
                                                xq, sx, B2, scale, Din, Dout);
  const int grid = (Mrows / 256) * (Dout / 256);  // 64 * 8 = 512
  gemm_kernel<<<grid, 512, 0, stream>>>(xq, B2, scale, bias, sx, out,
                                        Mrows, Dout, Din);
}

// Round 14
// 111.608 us; speedup vs baseline: 1.3164x; 1.0498x over previous
//
#include <hip/hip_runtime.h>
#include <stdint.h>

#define EPSF 1e-8f

using i32x4 = __attribute__((ext_vector_type(4))) int;

__device__ __forceinline__ float wave_bsum(float v) {
#pragma unroll
  for (int off = 1; off < 64; off <<= 1) v += __shfl_xor(v, off, 64);
  return v;
}
__device__ __forceinline__ float wave_bmax(float v) {
#pragma unroll
  for (int off = 1; off < 64; off <<= 1) v = fmaxf(v, __shfl_xor(v, off, 64));
  return v;
}

// ---------------- fused prep, wave-per-row (no LDS, no syncthreads) --------
// Each 64-lane wave owns one row; 4 independent waves per block.
//  waves [0, Dout)            : weight row -> ternary i8 wq + scale
//  waves [Dout, Dout+Mrows)   : x row -> RMSNorm*g -> i8 xq + sx
// Lane layout: lane reads 8 float4 at stride 64 (1 KB coalesced per instr);
// stores 8 dwords (4 packed i8) at stride 64 (256 B coalesced per instr).
__global__ __launch_bounds__(256) void prep_kernel(
    const float* __restrict__ x, const float* __restrict__ g,
    const float* __restrict__ w, const float* __restrict__ row_scale,
    signed char* __restrict__ xq, float* __restrict__ sx,
    signed char* __restrict__ wq, float* __restrict__ scale,
    int K, int Dout) {
  const int lane = threadIdx.x & 63;
  const int gw = (blockIdx.x << 2) | (threadIdx.x >> 6);  // global wave = row
  const int nf4 = K >> 2;        // float4 per row (512)
  if (gw < Dout) {
    const int o = gw;
    const float* wr = w + (size_t)o * K;
    float4 v[8];
#pragma unroll
    for (int c = 0; c < 8; ++c)
      v[c] = reinterpret_cast<const float4*>(wr)[c * 64 + lane];
    float sa = 0.f, sq = 0.f;
#pragma unroll
    for (int c = 0; c < 8; ++c) {
      sa += fabsf(v[c].x) + fabsf(v[c].y) + fabsf(v[c].z) + fabsf(v[c].w);
      sq += v[c].x * v[c].x + v[c].y * v[c].y + v[c].z * v[c].z + v[c].w * v[c].w;
    }
    sa = wave_bsum(sa);
    sq = wave_bsum(sq);
    const float absmean = sa / (float)K;
    const float thr = 0.5f * absmean;
    unsigned int* wq4 = reinterpret_cast<unsigned int*>(wq + (size_t)o * K);
#pragma unroll
    for (int c = 0; c < 8; ++c) {
      union { signed char b[4]; unsigned int u; } pk;
      const float f[4] = {v[c].x, v[c].y, v[c].z, v[c].w};
#pragma unroll
      for (int j = 0; j < 4; ++j)
        pk.b[j] = (fabsf(f[j]) > thr)
                      ? (f[j] > 0.f ? (signed char)1 : (signed char)-1)
                      : (signed char)0;
      wq4[c * 64 + lane] = pk.u;
    }
    if (lane == 0)
      scale[o] = absmean * rsqrtf(sq / (float)K + EPSF) * row_scale[o];
  } else if (gw < Dout + (int)(gridDim.x)) {
    // fallthrough guard never taken at our sizes; keep simple below
  }
  if (gw >= Dout) {
    const int row = gw - Dout;
    const float* xr = x + (size_t)row * K;
    float4 v[8];
#pragma unroll
    for (int c = 0; c < 8; ++c)
      v[c] = reinterpret_cast<const float4*>(xr)[c * 64 + lane];
    float sq = 0.f;
#pragma unroll
    for (int c = 0; c < 8; ++c)
      sq += v[c].x * v[c].x + v[c].y * v[c].y + v[c].z * v[c].z + v[c].w * v[c].w;
    sq = wave_bsum(sq);
    const float rs = rsqrtf(sq / (float)K + EPSF);
    float4 vv[8];
    float am = 0.f;
#pragma unroll
    for (int c = 0; c < 8; ++c) {
      const float4 gg = reinterpret_cast<const float4*>(g)[c * 64 + lane];
      vv[c].x = v[c].x * rs * gg.x; vv[c].y = v[c].y * rs * gg.y;
      vv[c].z = v[c].z * rs * gg.z; vv[c].w = v[c].w * rs * gg.w;
      am = fmaxf(am, fmaxf(fmaxf(fabsf(vv[c].x), fabsf(vv[c].y)),
                           fmaxf(fabsf(vv[c].z), fabsf(vv[c].w))));
    }
    am = wave_bmax(am);
    const float inv = am > 0.f ? 127.f / am : 0.f;
    unsigned int* xq4 = reinterpret_cast<unsigned int*>(xq + (size_t)row * K);
#pragma unroll
    for (int c = 0; c < 8; ++c) {
      union { signed char b[4]; unsigned int u; } pk;
      pk.b[0] = (signed char)__float2int_rn(vv[c].x * inv);
      pk.b[1] = (signed char)__float2int_rn(vv[c].y * inv);
      pk.b[2] = (signed char)__float2int_rn(vv[c].z * inv);
      pk.b[3] = (signed char)__float2int_rn(vv[c].w * inv);
      xq4[c * 64 + lane] = pk.u;
    }
    if (lane == 0) sx[row] = am > 0.f ? am / 127.f : 0.f;
  }
  (void)nf4;
}

// ---------------- i8 NT GEMM (ROUND-6 CHAMPION, verbatim) ----------------
// C[m,n] = sx[m]*scale[n]*sum_k qA[m,k]*t[n,k] + bias[n]; i32 dot exact.
// 512 threads = 8 waves (2M x 4N); per-wave 128x64; BK=128 i8; 16x16x64.
// XOR swizzle both-sides; one barrier per phase; counted vmcnt; peel with
// inline stores. Measured: gemm 76.6 us, MfmaUtil 36.8, conflicts 0.
// R7-R13 structural variants (32x32 shape, merged regions, 2-block/CU,
// persistent 2-tile, B-direct-VGPR coalesced) all landed 76-92 us ->
// this structure is the plain-HIP plateau; acc(128 AGPR)+~128 VGPR = 256
// unified regs pins 2 waves/SIMD for any 256-wide tile.

#define BAR() do { __builtin_amdgcn_sched_barrier(0); \
                   asm volatile("" ::: "memory"); \
                   __builtin_amdgcn_s_barrier(); \
                   asm volatile("" ::: "memory"); \
                   __builtin_amdgcn_sched_barrier(0); } while (0)
#define VM(n) asm volatile("s_waitcnt vmcnt(" #n ")" ::: "memory")

__global__ __launch_bounds__(512, 2) void gemm_kernel(
    const signed char* __restrict__ A,   // [M][K] i8 (xq)
    const signed char* __restrict__ B,   // [N][K] i8 ternary (wq)
    const float* __restrict__ scale, const float* __restrict__ bias,
    const float* __restrict__ sx,
    float* __restrict__ C, int M, int N, int K) {
  __shared__ signed char lds[2][2][2][16384];

  const int tid  = threadIdx.x;
  const int lane = tid & 63;
  const int wid  = tid >> 6;
  const int wm   = wid >> 2;   // 0..1
  const int wn   = wid & 3;    // 0..3
  const int fr   = lane & 15;
  const int kq   = lane >> 4;

  // chunked XCD swizzle (all 8 bn co-resident per XCD)
  const int nwg = gridDim.x;
  const int cpx = nwg >> 3;
  const int swz = (blockIdx.x & 7) * cpx + (blockIdx.x >> 3);
  const int NBN = N >> 8;
  const int bn = swz % NBN;
  const int bm = swz / NBN;
  const int mBase = bm * 256, nBase = bn * 256;

  const size_t Kb = (size_t)K;

  const int sr = tid >> 3;
  const int gsrc = (tid & 7) ^ (sr & 7);
  const char* Abyte = (const char*)A + (size_t)(mBase + sr) * Kb + gsrc * 16;
  const char* Bbyte = (const char*)B +
      (size_t)(nBase + ((sr >> 5) * 64) + (sr & 31)) * Kb + gsrc * 16;

#define STAGE_A(bufi, h, t) do { \
    __builtin_amdgcn_global_load_lds( \
      (const __attribute__((address_space(1))) void*)(Abyte + (size_t)((h) * 64) * Kb + (size_t)(t) * 128), \
      (__attribute__((address_space(3))) void*)(&lds[bufi][0][h][tid * 16]), 16, 0, 0); \
    __builtin_amdgcn_global_load_lds( \
      (const __attribute__((address_space(1))) void*)(Abyte + (size_t)(128 + (h) * 64) * Kb + (size_t)(t) * 128), \
      (__attribute__((address_space(3))) void*)(&lds[bufi][0][h][8192 + tid * 16]), 16, 0, 0); \
  } while (0)

#define STAGE_B(bufi, h, t) do { \
    __builtin_amdgcn_global_load_lds( \
      (const __attribute__((address_space(1))) void*)(Bbyte + (size_t)((h) * 32) * Kb + (size_t)(t) * 128), \
      (__attribute__((address_space(3))) void*)(&lds[bufi][1][h][tid * 16]), 16, 0, 0); \
    __builtin_amdgcn_global_load_lds( \
      (const __attribute__((address_space(1))) void*)(Bbyte + (size_t)(128 + (h) * 32) * Kb + (size_t)(t) * 128), \
      (__attribute__((address_space(3))) void*)(&lds[bufi][1][h][8192 + tid * 16]), 16, 0, 0); \
  } while (0)

  const int slot0 = ((kq ^ (fr & 7)) << 4);
  const int aRowB = (wm * 64 + fr) * 128;
  const int bRowB = (wn * 32 + fr) * 128;

  i32x4 aF[4][2], bF[4][2];
  i32x4 acc[8][4];
#pragma unroll
  for (int m = 0; m < 8; ++m)
#pragma unroll
    for (int n = 0; n < 4; ++n) acc[m][n] = (i32x4){0, 0, 0, 0};

#define LDA(bufi, mg) do { \
    _Pragma("unroll") for (int mm = 0; mm < 4; ++mm) \
    _Pragma("unroll") for (int s = 0; s < 2; ++s) \
      aF[mm][s] = *(const i32x4*)&lds[bufi][0][mg][ \
          aRowB + mm * 2048 + (slot0 ^ (s << 6))]; \
  } while (0)

#define LDB(bufi, np) do { \
    _Pragma("unroll") for (int nn = 0; nn < 2; ++nn) \
    _Pragma("unroll") for (int s = 0; s < 2; ++s) \
      bF[(np) * 2 + nn][s] = *(const i32x4*)&lds[bufi][1][np][ \
          bRowB + nn * 2048 + (slot0 ^ (s << 6))]; \
  } while (0)

#define MFMA_Q(mg, np) do { \
    __builtin_amdgcn_s_setprio(1); \
    _Pragma("unroll") for (int mm = 0; mm < 4; ++mm) \
    _Pragma("unroll") for (int nn = 0; nn < 2; ++nn) { \
      i32x4 c = acc[(mg) * 4 + mm][(np) * 2 + nn]; \
      c = __builtin_amdgcn_mfma_i32_16x16x64_i8(aF[mm][0], bF[(np) * 2 + nn][0], c, 0, 0, 0); \
      c = __builtin_amdgcn_mfma_i32_16x16x64_i8(aF[mm][1], bF[(np) * 2 + nn][1], c, 0, 0, 0); \
      acc[(mg) * 4 + mm][(np) * 2 + nn] = c; \
    } \
    __builtin_amdgcn_s_setprio(0); } while (0)

  const int crowBase = mBase + wm * 128 + kq * 4;
  const int ccolBase = nBase + wn * 64 + fr;

#define STORE_Q(mg, np) do { \
    float sxq_[4][4]; \
    _Pragma("unroll") for (int mm = 0; mm < 4; ++mm) \
    _Pragma("unroll") for (int r = 0; r < 4; ++r) \
      sxq_[mm][r] = sx[crowBase + ((mg) * 4 + mm) * 16 + r]; \
    _Pragma("unroll") for (int nn = 0; nn < 2; ++nn) { \
      const int gc = ccolBase + ((np) * 2 + nn) * 16; \
      const float sc = scale[gc]; \
      const float bi = bias[gc]; \
      _Pragma("unroll") for (int mm = 0; mm < 4; ++mm) { \
        const int r0 = crowBase + ((mg) * 4 + mm) * 16; \
        _Pragma("unroll") for (int r = 0; r < 4; ++r) \
          C[(size_t)(r0 + r) * (size_t)N + (size_t)gc] = \
              (float)acc[(mg) * 4 + mm][(np) * 2 + nn][r] * (sxq_[mm][r] * sc) + bi; \
      } } } while (0)

  // ---- prologue: tile0 complete, tile1 h0 halves ----
  STAGE_A(0, 0, 0); STAGE_B(0, 0, 0);
  STAGE_A(0, 1, 0); STAGE_B(0, 1, 0);
  STAGE_A(1, 0, 1); STAGE_B(1, 0, 1);
  VM(8);
  BAR();

  const int NT = K >> 7;  // 2048/128 = 16; 7 iters + peel
  for (int i = 0; i < (NT >> 1) - 1; ++i) {
    const int t1  = 2 * i + 1;
    const int tn0 = 2 * i + 2;
    const int tn1 = 2 * i + 3;
    // P1
    LDA(0, 0); LDB(0, 0); STAGE_A(1, 1, t1); VM(6);
    BAR(); MFMA_Q(0, 0);
    // P2
    LDB(0, 1); STAGE_B(1, 1, t1);
    BAR(); MFMA_Q(0, 1);
    // P3
    LDA(0, 1); STAGE_A(0, 0, tn0);
    BAR(); MFMA_Q(1, 0);
    // P4
    STAGE_B(0, 0, tn0); VM(8);
    BAR(); MFMA_Q(1, 1);
    // P5
    LDA(1, 0); LDB(1, 0); STAGE_A(0, 1, tn0); VM(6);
    BAR(); MFMA_Q(0, 0);
    // P6
    LDB(1, 1); STAGE_B(0, 1, tn0);
    BAR(); MFMA_Q(0, 1);
    // P7
    LDA(1, 1); STAGE_A(1, 0, tn1);
    BAR(); MFMA_Q(1, 0);
    // P8
    STAGE_B(1, 0, tn1); VM(8);
    BAR(); MFMA_Q(1, 1);
  }

  // ---- peeled last iteration ----
  {
    const int tl = NT - 1;
    LDA(0, 0); LDB(0, 0); STAGE_A(1, 1, tl); VM(6);
    BAR(); MFMA_Q(0, 0);
    LDB(0, 1); STAGE_B(1, 1, tl);
    BAR(); MFMA_Q(0, 1);
    LDA(0, 1);
    BAR(); MFMA_Q(1, 0);
    VM(4);
    BAR(); MFMA_Q(1, 1);
    LDA(1, 0); LDB(1, 0); VM(0);
    BAR(); MFMA_Q(0, 0); STORE_Q(0, 0);
    LDB(1, 1);
    BAR(); MFMA_Q(0, 1); STORE_Q(0, 1);
    LDA(1, 1);
    BAR(); MFMA_Q(1, 0); STORE_Q(1, 0);
    BAR(); MFMA_Q(1, 1); STORE_Q(1, 1);
  }
#undef STAGE_A
#undef STAGE_B
#undef LDA
#undef LDB
#undef MFMA_Q
#undef STORE_Q
}

extern "C" void kernel_launch(void* const* d_in, const int* in_sizes, int n_in,
                              void* d_out, int out_size, void* d_ws, size_t ws_size,
                              hipStream_t stream) {
  const float* x         = (const float*)d_in[0];  // [B,S,Din]
  const float* weight    = (const float*)d_in[1];  // [Dout,Din]
  const float* row_scale = (const float*)d_in[2];  // [Dout,1]
  const float* bias      = (const float*)d_in[3];  // [Dout]
  const float* g         = (const float*)d_in[4];  // [Din]
  float* out = (float*)d_out;

  const int Din  = in_sizes[4];         // 2048
  const int Dout = in_sizes[3];         // 2048
  const int Mrows = in_sizes[0] / Din;  // 16384

  // ws: wq i8 [Dout*Din] | xq i8 [M*Din] | scale f32 [Dout] | sx f32 [M]
  char* ws = (char*)d_ws;
  signed char* wq = (signed char*)ws;
  signed char* xq = (signed char*)(ws + (size_t)Dout * Din);
  float* scale = (float*)(ws + (size_t)Dout * Din + (size_t)Mrows * Din);
  float* sx = scale + Dout;

  prep_kernel<<<(Dout + Mrows) / 4, 256, 0, stream>>>(
      x, g, weight, row_scale, xq, sx, wq, scale, Din, Dout);
  const int grid = (Mrows / 256) * (Dout / 256);  // 64 * 8 = 512
  gemm_kernel<<<grid, 512, 0, stream>>>(xq, wq, scale, bias, sx, out,
                                        Mrows, Dout, Din);
}